// Round 7
// baseline (90.271 us; speedup 1.0000x reference)
//
#include <hip/hip_runtime.h>
#include <hip/hip_bf16.h>

// Problem: N=64, K=512, D=256. Reference reduces to out = relu(x @ W^T + b):
// softmax over j sums to 1 and einsum 'nkj,nkd->nkd' multiplies h by that sum.
// [32768,256] x [256,256]^T GEMM + bias + ReLU. Memory-bound (~67 MB HBM).
//
// R1: register-resident B, 128-VGPR cap -> AGPR-ized+serialized, 42us.
// R2/R3: LDS W-slice + deep A-prefetch -> ~35us (divergent loads).
// R4: coalesced LDS staging -> ~29us (4x redundant x reads).
// R5: persistent full-W block, x read once -> ~17us.
// R6: lgkm-only barriers -> neutral (barrier drain wasn't the limiter).
// R7: each wave only needs ITS 32 W-rows -> B-frags in registers, loaded
//     via 16 coalesced dwordx4 from a fragment-ordered bf16 W (tiny cast
//     kernel into d_ws). No lw, no staging barrier. Freed LDS -> double-
//     buffered lx, 1 barrier/tile, stores drain in background.

#define DD 256          // feature dim
#define M_TOTAL 32768   // N*K rows
#define LWS 264         // LDS row stride in shorts (528 B): measured 0 conflicts

typedef short bf16x8 __attribute__((ext_vector_type(8)));
typedef float floatx16 __attribute__((ext_vector_type(16)));

// LDS-only barrier (CK block_sync_lds pattern): global loads/stores stay
// in flight across it.
#define BAR() asm volatile("s_waitcnt lgkmcnt(0)\n\ts_barrier" ::: "memory")

// Pack 8 fp32 -> 8 bf16 (packed cvt, RNE).
__device__ inline bf16x8 pack8(float4 p0, float4 p1) {
    __hip_bfloat162 q0 = __float22bfloat162_rn(make_float2(p0.x, p0.y));
    __hip_bfloat162 q1 = __float22bfloat162_rn(make_float2(p0.z, p0.w));
    __hip_bfloat162 q2 = __float22bfloat162_rn(make_float2(p1.x, p1.y));
    __hip_bfloat162 q3 = __float22bfloat162_rn(make_float2(p1.z, p1.w));
    union { bf16x8 v; unsigned u[4]; } r;
    union { __hip_bfloat162 h; unsigned u; } c;
    c.h = q0; r.u[0] = c.u;
    c.h = q1; r.u[1] = c.u;
    c.h = q2; r.u[2] = c.u;
    c.h = q3; r.u[3] = c.u;
    return r.v;
}

// W fp32 [256,256] -> bf16 fragment-ordered: element (w,s,lane,j) =
// W[w*32 + (lane&31)][s*16 + (lane>>5)*8 + j].  8192 threads x one bf16x8.
__global__ void cast_w_frag(const float* __restrict__ W,
                            unsigned short* __restrict__ Wb) {
    const int gid  = blockIdx.x * 256 + threadIdx.x;  // 0..8191
    const int w    = gid >> 10;
    const int s    = (gid >> 6) & 15;
    const int lane = gid & 63;
    const int e    = w * 32 + (lane & 31);
    const int k0   = s * 16 + (lane >> 5) * 8;
    const float* src = W + e * DD + k0;
    float4 a0 = *(const float4*)(src);
    float4 a1 = *(const float4*)(src + 4);
    *(bf16x8*)(Wb + gid * 8) = pack8(a0, a1);
}

// Each thread's share of one 32-row x tile: rows r0, r0+16, 8 floats at c0.
__device__ inline void load_tile(const float* __restrict__ x, int m0,
                                 int r0, int c0, float4 P[4]) {
    const float* s0 = x + (m0 + r0) * DD + c0;
    const float* s1 = x + (m0 + 16 + r0) * DD + c0;
    P[0] = *(const float4*)(s0);
    P[1] = *(const float4*)(s0 + 4);
    P[2] = *(const float4*)(s1);
    P[3] = *(const float4*)(s1 + 4);
}

__device__ inline void write_lx(unsigned short* lx, int r0, int c0,
                                const float4 P[4]) {
    *(bf16x8*)(lx + r0 * LWS + c0)        = pack8(P[0], P[1]);
    *(bf16x8*)(lx + (16 + r0) * LWS + c0) = pack8(P[2], P[3]);
}

__device__ inline void compute_tile(const unsigned short* ap,
                                    const bf16x8 Bf[16], floatx16& acc) {
#pragma unroll
    for (int i = 0; i < 16; ++i) acc[i] = 0.f;
#pragma unroll
    for (int s = 0; s < 16; ++s) {
        bf16x8 af = *(const bf16x8*)(ap + s * 16);
        acc = __builtin_amdgcn_mfma_f32_32x32x16_bf16(af, Bf[s], acc, 0, 0, 0);
    }
}

// C/D layout: col = lane&31, row = (reg&3) + 8*(reg>>2) + 4*(lane>>5)
__device__ inline void store_tile(float* ob, int m0, int lh, float bias,
                                  const floatx16& acc) {
#pragma unroll
    for (int r = 0; r < 16; ++r) {
        const int m = m0 + (r & 3) + 8 * (r >> 2) + 4 * lh;
        float v = acc[r] + bias;
        v = v > 0.f ? v : 0.f;
        __builtin_nontemporal_store(v, ob + m * DD);
    }
}

// 512 thr = 8 waves; wave w owns e-strip [w*32, w*32+32) with its B-frags
// in registers. Block owns 128 m-rows = 4 tiles of 32. Grid = 256 (1/CU).
__global__ void __launch_bounds__(512, 1)
fcgat_gemm(const float* __restrict__ x, const unsigned short* __restrict__ Wb,
           const float* __restrict__ Wbias, float* __restrict__ out) {
    __shared__ __align__(16) unsigned short lx0[32 * LWS];  // 16.5 KB
    __shared__ __align__(16) unsigned short lx1[32 * LWS];  // 16.5 KB

    const int tid   = threadIdx.x;        // 0..511
    const int r0    = tid >> 5;           // 0..15 (staging row base)
    const int c0    = (tid & 31) * 8;     // staging col (floats/shorts)
    const int mbase = blockIdx.x * 128;
    const int lane  = tid & 63;
    const int wave  = tid >> 6;           // 0..7 -> e-strip

    // ---- issue x tile0+tile1 prefetch first ----
    float4 Pa[4], Pb[4];
    load_tile(x, mbase + 0,  r0, c0, Pa);
    load_tile(x, mbase + 32, r0, c0, Pb);

    // ---- B-fragments: 16 coalesced dwordx4 loads, register-resident ----
    bf16x8 Bf[16];
    {
        const unsigned short* wb = Wb + wave * 8192 + lane * 8;
#pragma unroll
        for (int s = 0; s < 16; ++s)
            Bf[s] = *(const bf16x8*)(wb + s * 512);
    }

    write_lx(lx0, r0, c0, Pa);            // waits only Pa's loads
    BAR();

    const int ln = lane & 31;
    const int lh = lane >> 5;             // k-half (0/1)
    const unsigned short* ap0 = lx0 + ln * LWS + lh * 8;
    const unsigned short* ap1 = lx1 + ln * LWS + lh * 8;
    const float bias = Wbias[wave * 32 + ln];
    float* ob = out + wave * 32 + ln;

    floatx16 acc;

    // ---- tile 0: compute lx0, fill lx1, prefetch tile2 ----
    compute_tile(ap0, Bf, acc);
    write_lx(lx1, r0, c0, Pb);
    load_tile(x, mbase + 64, r0, c0, Pa);
    BAR();
    store_tile(ob, mbase + 0, lh, bias, acc);

    // ---- tile 1: compute lx1, fill lx0, prefetch tile3 ----
    compute_tile(ap1, Bf, acc);
    write_lx(lx0, r0, c0, Pa);
    load_tile(x, mbase + 96, r0, c0, Pb);
    BAR();
    store_tile(ob, mbase + 32, lh, bias, acc);

    // ---- tile 2: compute lx0, fill lx1 ----
    compute_tile(ap0, Bf, acc);
    write_lx(lx1, r0, c0, Pb);
    BAR();
    store_tile(ob, mbase + 64, lh, bias, acc);

    // ---- tile 3 ----
    compute_tile(ap1, Bf, acc);
    store_tile(ob, mbase + 96, lh, bias, acc);
}

extern "C" void kernel_launch(void* const* d_in, const int* in_sizes, int n_in,
                              void* d_out, int out_size, void* d_ws, size_t ws_size,
                              hipStream_t stream) {
    const float* x    = (const float*)d_in[0];  // [64,512,256]
    const float* W_w  = (const float*)d_in[1];  // [256,256]
    const float* W_b  = (const float*)d_in[2];  // [256]
    // d_in[3] = att_w, d_in[4] = att_b — provably unused (softmax sums to 1)
    float* out = (float*)d_out;                 // [64,512,256] fp32
    unsigned short* Wb = (unsigned short*)d_ws; // 128 KB bf16 frag-ordered W

    cast_w_frag<<<32, 256, 0, stream>>>(W_w, Wb);
    fcgat_gemm<<<M_TOTAL / 128, 512, 0, stream>>>(x, Wb, W_b, out);
}